// Round 10
// baseline (139.710 us; speedup 1.0000x reference)
//
#include <hip/hip_runtime.h>
#include <hip/hip_fp16.h>

#define NN   512
#define D    128      // INPUT_DIM
#define HID  256      // HIDDEN_DIM
#define REL  128      // REL_DIM
#define ODIM 64

typedef __attribute__((ext_vector_type(4)))  float        f32x4;
typedef __attribute__((ext_vector_type(16))) float        f32x16;
typedef __attribute__((ext_vector_type(8)))  _Float16     f16x8;
typedef __attribute__((ext_vector_type(4)))  unsigned int u32x4;

union H8 { u32x4 u4; f16x8 h8; };

#define WAIT_VM(N) asm volatile("s_waitcnt vmcnt(" #N ")" ::: "memory")

__device__ __forceinline__ void cp16(void* l, const void* g) {
    __builtin_amdgcn_global_load_lds((const __attribute__((address_space(1))) unsigned int*)g,
                                     (__attribute__((address_space(3))) unsigned int*)l, 16, 0, 0);
}

// ---------------- kAW: blocks 0..127 compute A'(fp16, row-major) and B (fp16, frag-major Bg);
//                  blocks 128..143 pack W2 into 32x32x16 B-fragment order (W2g).
__global__ void kAW(const float* __restrict__ X, const float* __restrict__ W1,
                    const float* __restrict__ b1, _Float16* __restrict__ Aph,
                    _Float16* __restrict__ Bg,
                    const float* __restrict__ W2, _Float16* __restrict__ W2g) {
    int t = threadIdx.x;            // 0..255
    if (blockIdx.x >= 128) {        // ---- W2 pack
        int gid = (blockIdx.x - 128) * 256 + t;   // 0..4095
        int f = gid >> 6, l = gid & 63;
        int cg = f >> 4, ks = f & 15;
        H8 pkd;
#pragma unroll
        for (int e = 0; e < 8; ++e) {
            int k = ks * 16 + (l >> 5) * 8 + e;
            int c = cg * 32 + (l & 31);
            pkd.h8[e] = (_Float16)W2[k * REL + c];
        }
        *(u32x4*)&W2g[(size_t)gid * 8] = pkd.u4;
        return;
    }
    __shared__ float Xs[4][D];
    int r0 = blockIdx.x * 4;
#pragma unroll
    for (int q = 0; q < 2; ++q) {
        int idx = q * 256 + t;
        Xs[idx >> 7][idx & 127] = X[(r0 + (idx >> 7)) * D + (idx & 127)];
    }
    __syncthreads();
    float a[4], b[4];
    float b1c = b1[t];
#pragma unroll
    for (int r = 0; r < 4; ++r) { a[r] = b1c; b[r] = 0.f; }
#pragma unroll 4
    for (int k = 0; k < D; ++k) {
        float wt = W1[k * HID + t];
        float wb = W1[(D + k) * HID + t];
#pragma unroll
        for (int r = 0; r < 4; ++r) {
            a[r] += Xs[r][k] * wt;
            b[r] += Xs[r][k] * wb;
        }
    }
    int ks = t >> 4, hs = (t >> 3) & 1, e = t & 7;
#pragma unroll
    for (int r = 0; r < 4; ++r) {
        int row = r0 + r;
        Aph[row * HID + t] = (_Float16)a[r];
        Bg[(row >> 4) * 4096 + ks * 256 + hs * 128 + (row & 15) * 8 + e] = (_Float16)b[r];
    }
}

// ---------------- kB: R7 structure, 8x internal repeat for PROFILING (reps 0..6 kept
// alive via asm, only rep 7 contributes -> output bit-identical to R7).
__global__ __launch_bounds__(256, 2) void kB(const _Float16* __restrict__ Aph,
                                             const _Float16* __restrict__ Bg,
                                             const _Float16* __restrict__ W2g,
                                             const float* __restrict__ b2,
                                             float* __restrict__ partial) {
    __shared__ __align__(16) char smem[2][4096];   // A double-buffer: [buf][wave 1KB slices]
    __shared__ float redsh[4][2][32];

    int t = threadIdx.x, w = t >> 6, l = t & 63;
    int blk = blockIdx.x;
    int ch = blk & 1, tg = blk >> 1;
    int jt = tg & 31, itb = tg >> 5;     // j-tile (block-constant), i-tile base
    int l31 = l & 31, hs = l >> 5, j = l & 15;

    // W2 register fragments: 2 col-groups x 16 k-steps (128 VGPR), loaded once
    H8 w2r[2][16];
#pragma unroll
    for (int cgi = 0; cgi < 2; ++cgi)
#pragma unroll
        for (int ks = 0; ks < 16; ++ks)
            w2r[cgi][ks].u4 = *(const u32x4*)&W2g[(size_t)((((ch * 2 + cgi) * 16 + ks) * 64) + l) * 8];

    // B register fragments for this lane's (j, hs): 16 k-steps (64 VGPR), block-constant
    H8 brow[16];
#pragma unroll
    for (int ks = 0; ks < 16; ++ks)
        brow[ks].u4 = *(const u32x4*)&Bg[(size_t)jt * 4096 + ks * 256 + hs * 128 + j * 8];

    float b2c0 = b2[ch * 64 + l31];
    float b2c1 = b2[ch * 64 + 32 + l31];

    const f16x8 zero8 = (f16x8)(_Float16)0.f;
    float psum0 = 0.f, psum1 = 0.f;

#pragma unroll 1
    for (int rep = 0; rep < 8; ++rep) {
        // prologue: stage unit 0's A rows for this wave (1 KB)
        cp16(&smem[0][w * 1024 + l * 16], &Aph[(itb * 8 + 2 * w + hs) * HID + l31 * 8]);

#pragma unroll 1
        for (int u = 0; u < 8; ++u) {
            int cur = u & 1;
            if (u < 7) {
                int i0n = itb * 8 + (u + 1) * 64;
                cp16(&smem[cur ^ 1][w * 1024 + l * 16], &Aph[(i0n + 2 * w + hs) * HID + l31 * 8]);
                WAIT_VM(1);
            } else {
                WAIT_VM(0);
            }
            // no barrier: this wave reads only the rows it staged itself

            const char* abase = &smem[cur][w * 1024 + (l31 >> 4) * 512 + hs * 16];

            f32x16 acc0, acc1;
#pragma unroll
            for (int r = 0; r < 16; ++r) { acc0[r] = 0.f; acc1[r] = 0.f; }

#pragma unroll
            for (int ks = 0; ks < 16; ++ks) {
                H8 a = *(const H8*)(abase + ks * 32);
                f16x8 sum = a.h8 + brow[ks].h8;                       // v_pk_add_f16 x4
                H8 h; h.h8 = __builtin_elementwise_max(sum, zero8);   // v_pk_max_f16 x4
                acc0 = __builtin_amdgcn_mfma_f32_32x32x16_f16(h.h8, w2r[0][ks].h8, acc0, 0, 0, 0);
                acc1 = __builtin_amdgcn_mfma_f32_32x32x16_f16(h.h8, w2r[1][ks].h8, acc1, 0, 0, 0);
            }

            float s0 = 0.f, s1 = 0.f;
#pragma unroll
            for (int r = 0; r < 16; ++r) {
                s0 += fmaxf(acc0[r] + b2c0, 0.f);
                s1 += fmaxf(acc1[r] + b2c1, 0.f);
            }
            asm volatile("" :: "v"(s0), "v"(s1));   // keep reps 0..6 live (no DCE)
            if (rep == 7) { psum0 += s0; psum1 += s1; }
        }
    }

    // block reduction: combine row-halves, then the 4 waves
    psum0 += __shfl_xor(psum0, 32);
    psum1 += __shfl_xor(psum1, 32);
    if (l < 32) { redsh[w][0][l] = psum0; redsh[w][1][l] = psum1; }
    __syncthreads();
    if (w == 0 && l < 32) {
        float t0 = redsh[0][0][l] + redsh[1][0][l] + redsh[2][0][l] + redsh[3][0][l];
        float t1 = redsh[0][1][l] + redsh[1][1][l] + redsh[2][1][l] + redsh[3][1][l];
        partial[blk * 64 + l]      = t0;
        partial[blk * 64 + 32 + l] = t1;
    }
}

// ---------------- kRC: reduce 512 per-block partials -> R (mean), then final tiny MLP
__global__ void kRC(const float* __restrict__ partial,
                    const float* __restrict__ W3, const float* __restrict__ b3,
                    const float* __restrict__ W4, const float* __restrict__ b4,
                    float* __restrict__ out) {
    __shared__ float sh[256];
    __shared__ float Rsh[REL];
    __shared__ float t1[ODIM];
    int t = threadIdx.x;                 // 256
    int c = t & 127, g = t >> 7;
    int ch = c >> 6, cc = c & 63;
    float s = 0.f;
#pragma unroll 4
    for (int k = g * 128; k < g * 128 + 128; ++k)
        s += partial[(2 * k + ch) * 64 + cc];
    sh[t] = s;
    __syncthreads();
    if (t < 128) Rsh[t] = (sh[t] + sh[t + 128]) * (1.f / 262144.f);
    __syncthreads();
    if (t < ODIM) {
        float s3 = b3[t];
#pragma unroll 8
        for (int k = 0; k < REL; ++k) s3 += Rsh[k] * W3[k * ODIM + t];
        t1[t] = fmaxf(s3, 0.f);
    }
    __syncthreads();
    if (t < ODIM) {
        float s4 = b4[t];
#pragma unroll 8
        for (int k = 0; k < ODIM; ++k) s4 += t1[k] * W4[k * ODIM + t];
        out[t] = s4;
    }
}

extern "C" void kernel_launch(void* const* d_in, const int* in_sizes, int n_in,
                              void* d_out, int out_size, void* d_ws, size_t ws_size,
                              hipStream_t stream) {
    const float* X  = (const float*)d_in[0];
    const float* W1 = (const float*)d_in[1];
    const float* b1 = (const float*)d_in[2];
    const float* W2 = (const float*)d_in[3];
    const float* b2 = (const float*)d_in[4];
    const float* W3 = (const float*)d_in[5];
    const float* b3 = (const float*)d_in[6];
    const float* W4 = (const float*)d_in[7];
    const float* b4 = (const float*)d_in[8];
    float* out = (float*)d_out;

    char* ws = (char*)d_ws;
    _Float16* Aph     = (_Float16*)ws;                 // 512*256 fp16 = 256 KB
    _Float16* Bg      = (_Float16*)(ws + 262144);      // 32 jt * 8 KB = 256 KB
    _Float16* W2g     = (_Float16*)(ws + 524288);      // 64 frags * 1 KB = 64 KB
    float*    partial = (float*)(ws + 589824);         // 512*64 f32 = 128 KB

    kAW<<<144, 256, 0, stream>>>(X, W1, b1, Aph, Bg, W2, W2g);
    kB<<<512, 256, 0, stream>>>(Aph, Bg, W2g, b2, partial);
    kRC<<<1, 256, 0, stream>>>(partial, W3, b3, W4, b4, out);
}

// Round 11
// 51.312 us; speedup vs baseline: 2.7227x; 2.7227x over previous
//
#include <hip/hip_runtime.h>
#include <hip/hip_fp16.h>

#define NN   512
#define D    128      // INPUT_DIM
#define HID  256      // HIDDEN_DIM
#define REL  128      // REL_DIM
#define ODIM 64

typedef __attribute__((ext_vector_type(4)))  float        f32x4;
typedef __attribute__((ext_vector_type(16))) float        f32x16;
typedef __attribute__((ext_vector_type(8)))  _Float16     f16x8;
typedef __attribute__((ext_vector_type(4)))  unsigned int u32x4;

union H8 { u32x4 u4; f16x8 h8; };

#define WAIT_VM(N) asm volatile("s_waitcnt vmcnt(" #N ")" ::: "memory")

__device__ __forceinline__ void cp16(void* l, const void* g) {
    __builtin_amdgcn_global_load_lds((const __attribute__((address_space(1))) unsigned int*)g,
                                     (__attribute__((address_space(3))) unsigned int*)l, 16, 0, 0);
}

// ---------------- kAW: blocks 0..127 compute A'(fp16, row-major) and B (fp16, frag-major Bg);
//                  blocks 128..143 pack W2 into 32x32x16 B-fragment order (W2g).
__global__ void kAW(const float* __restrict__ X, const float* __restrict__ W1,
                    const float* __restrict__ b1, _Float16* __restrict__ Aph,
                    _Float16* __restrict__ Bg,
                    const float* __restrict__ W2, _Float16* __restrict__ W2g) {
    int t = threadIdx.x;            // 0..255
    if (blockIdx.x >= 128) {        // ---- W2 pack
        int gid = (blockIdx.x - 128) * 256 + t;   // 0..4095
        int f = gid >> 6, l = gid & 63;
        int cg = f >> 4, ks = f & 15;
        H8 pkd;
#pragma unroll
        for (int e = 0; e < 8; ++e) {
            int k = ks * 16 + (l >> 5) * 8 + e;
            int c = cg * 32 + (l & 31);
            pkd.h8[e] = (_Float16)W2[k * REL + c];
        }
        *(u32x4*)&W2g[(size_t)gid * 8] = pkd.u4;
        return;
    }
    __shared__ float Xs[4][D];
    int r0 = blockIdx.x * 4;
#pragma unroll
    for (int q = 0; q < 2; ++q) {
        int idx = q * 256 + t;
        Xs[idx >> 7][idx & 127] = X[(r0 + (idx >> 7)) * D + (idx & 127)];
    }
    __syncthreads();
    float a[4], b[4];
    float b1c = b1[t];
#pragma unroll
    for (int r = 0; r < 4; ++r) { a[r] = b1c; b[r] = 0.f; }
#pragma unroll 4
    for (int k = 0; k < D; ++k) {
        float wt = W1[k * HID + t];
        float wb = W1[(D + k) * HID + t];
#pragma unroll
        for (int r = 0; r < 4; ++r) {
            a[r] += Xs[r][k] * wt;
            b[r] += Xs[r][k] * wb;
        }
    }
    int ks = t >> 4, hs = (t >> 3) & 1, e = t & 7;
#pragma unroll
    for (int r = 0; r < 4; ++r) {
        int row = r0 + r;
        Aph[row * HID + t] = (_Float16)a[r];
        Bg[(row >> 4) * 4096 + ks * 256 + hs * 128 + (row & 15) * 8 + e] = (_Float16)b[r];
    }
}

// ---------------- kB: 32x32x16 MFMA pair GEMM. Grid 1024 (4 blocks/CU), 4 waves.
// blk: ch = blk&1 (64-col half), rest = blk>>1: jt = rest&31, itb = rest>>5 (0..15).
// 4 units: i0 = itb*8 + u*128. Wave w owns rows {2w, 2w+1} (32 pairs = 2i x 16j).
// W2 (128 VGPR) + B (64 VGPR) register-resident. A staged per unit via cp16 into the
// wave's own 1KB slice with CONFLICT-FREE layout: byte = ks*64 + row*32 + hs*16
// (per-ds_read addrs {0,16,32,48}+ks*64 -> 16 consecutive banks, 16-way broadcast).
__global__ __launch_bounds__(256, 2) void kB(const _Float16* __restrict__ Aph,
                                             const _Float16* __restrict__ Bg,
                                             const _Float16* __restrict__ W2g,
                                             const float* __restrict__ b2,
                                             float* __restrict__ partial) {
    __shared__ __align__(16) char smem[2][4096];   // A double-buffer: [buf][wave 1KB slices]
    __shared__ float redsh[4][2][32];

    int t = threadIdx.x, w = t >> 6, l = t & 63;
    int blk = blockIdx.x;
    int ch = blk & 1, rest = blk >> 1;
    int jt = rest & 31, itb = rest >> 5;   // j-tile (block-constant), i-tile base 0..15
    int l31 = l & 31, hs = l >> 5, j = l & 15;

    // W2 register fragments: 2 col-groups x 16 k-steps (128 VGPR), loaded once
    H8 w2r[2][16];
#pragma unroll
    for (int cgi = 0; cgi < 2; ++cgi)
#pragma unroll
        for (int ks = 0; ks < 16; ++ks)
            w2r[cgi][ks].u4 = *(const u32x4*)&W2g[(size_t)((((ch * 2 + cgi) * 16 + ks) * 64) + l) * 8];

    // B register fragments for this lane's (j, hs): 16 k-steps (64 VGPR), block-constant
    H8 brow[16];
#pragma unroll
    for (int ks = 0; ks < 16; ++ks)
        brow[ks].u4 = *(const u32x4*)&Bg[(size_t)jt * 4096 + ks * 256 + hs * 128 + j * 8];

    float b2c0 = b2[ch * 64 + l31];
    float b2c1 = b2[ch * 64 + 32 + l31];

    const f16x8 zero8 = (f16x8)(_Float16)0.f;
    float psum0 = 0.f, psum1 = 0.f;

    // staging source for this lane: row = (l>>1)&1, col halves = (l>>2)*16 + (l&1)*8
    // (so LDS byte l*16 = ks*64 + row*32 + hs*16 holds A'[i0+2w+row][ks*16+hs*8..+8])
    int srow = (l >> 1) & 1, scol = ((l >> 2) << 4) + ((l & 1) << 3);

    // prologue: stage unit 0's A rows for this wave (1 KB)
    cp16(&smem[0][w * 1024 + l * 16], &Aph[(itb * 8 + 2 * w + srow) * HID + scol]);

#pragma unroll 1
    for (int u = 0; u < 4; ++u) {
        int cur = u & 1;
        if (u < 3) {
            int i0n = itb * 8 + (u + 1) * 128;
            cp16(&smem[cur ^ 1][w * 1024 + l * 16], &Aph[(i0n + 2 * w + srow) * HID + scol]);
            WAIT_VM(1);
        } else {
            WAIT_VM(0);
        }
        // no barrier: this wave reads only the slice it staged itself

        const char* abase = &smem[cur][w * 1024 + (l31 >> 4) * 32 + hs * 16];

        f32x16 acc0, acc1;
#pragma unroll
        for (int r = 0; r < 16; ++r) { acc0[r] = 0.f; acc1[r] = 0.f; }

#pragma unroll
        for (int ks = 0; ks < 16; ++ks) {
            H8 a = *(const H8*)(abase + ks * 64);
            f16x8 sum = a.h8 + brow[ks].h8;                       // v_pk_add_f16 x4
            H8 h; h.h8 = __builtin_elementwise_max(sum, zero8);   // v_pk_max_f16 x4
            acc0 = __builtin_amdgcn_mfma_f32_32x32x16_f16(h.h8, w2r[0][ks].h8, acc0, 0, 0, 0);
            acc1 = __builtin_amdgcn_mfma_f32_32x32x16_f16(h.h8, w2r[1][ks].h8, acc1, 0, 0, 0);
        }

        // per-unit epilogue: relu(acc + b2), sum over this lane's 16 pair-rows
        float s0 = 0.f, s1 = 0.f;
#pragma unroll
        for (int r = 0; r < 16; ++r) {
            s0 += fmaxf(acc0[r] + b2c0, 0.f);
            s1 += fmaxf(acc1[r] + b2c1, 0.f);
        }
        psum0 += s0; psum1 += s1;
    }

    // block reduction: combine row-halves, then the 4 waves
    psum0 += __shfl_xor(psum0, 32);
    psum1 += __shfl_xor(psum1, 32);
    if (l < 32) { redsh[w][0][l] = psum0; redsh[w][1][l] = psum1; }
    __syncthreads();
    if (w == 0 && l < 32) {
        float t0 = redsh[0][0][l] + redsh[1][0][l] + redsh[2][0][l] + redsh[3][0][l];
        float t1 = redsh[0][1][l] + redsh[1][1][l] + redsh[2][1][l] + redsh[3][1][l];
        partial[blk * 64 + l]      = t0;
        partial[blk * 64 + 32 + l] = t1;
    }
}

// ---------------- kRC: reduce 1024 per-block partials -> R (mean), then final tiny MLP
__global__ void kRC(const float* __restrict__ partial,
                    const float* __restrict__ W3, const float* __restrict__ b3,
                    const float* __restrict__ W4, const float* __restrict__ b4,
                    float* __restrict__ out) {
    __shared__ float sh[256];
    __shared__ float Rsh[REL];
    __shared__ float t1[ODIM];
    int t = threadIdx.x;                 // 256
    int c = t & 127, g = t >> 7;
    int ch = c >> 6, cc = c & 63;
    float s = 0.f;
#pragma unroll 4
    for (int m = g * 256; m < g * 256 + 256; ++m)
        s += partial[(2 * m + ch) * 64 + cc];
    sh[t] = s;
    __syncthreads();
    if (t < 128) Rsh[t] = (sh[t] + sh[t + 128]) * (1.f / 262144.f);
    __syncthreads();
    if (t < ODIM) {
        float s3 = b3[t];
#pragma unroll 8
        for (int k = 0; k < REL; ++k) s3 += Rsh[k] * W3[k * ODIM + t];
        t1[t] = fmaxf(s3, 0.f);
    }
    __syncthreads();
    if (t < ODIM) {
        float s4 = b4[t];
#pragma unroll 8
        for (int k = 0; k < ODIM; ++k) s4 += t1[k] * W4[k * ODIM + t];
        out[t] = s4;
    }
}

extern "C" void kernel_launch(void* const* d_in, const int* in_sizes, int n_in,
                              void* d_out, int out_size, void* d_ws, size_t ws_size,
                              hipStream_t stream) {
    const float* X  = (const float*)d_in[0];
    const float* W1 = (const float*)d_in[1];
    const float* b1 = (const float*)d_in[2];
    const float* W2 = (const float*)d_in[3];
    const float* b2 = (const float*)d_in[4];
    const float* W3 = (const float*)d_in[5];
    const float* b3 = (const float*)d_in[6];
    const float* W4 = (const float*)d_in[7];
    const float* b4 = (const float*)d_in[8];
    float* out = (float*)d_out;

    char* ws = (char*)d_ws;
    _Float16* Aph     = (_Float16*)ws;                 // 512*256 fp16 = 256 KB
    _Float16* Bg      = (_Float16*)(ws + 262144);      // 32 jt * 8 KB = 256 KB
    _Float16* W2g     = (_Float16*)(ws + 524288);      // 64 frags * 1 KB = 64 KB
    float*    partial = (float*)(ws + 589824);         // 1024*64 f32 = 256 KB

    kAW<<<144, 256, 0, stream>>>(X, W1, b1, Aph, Bg, W2, W2g);
    kB<<<1024, 256, 0, stream>>>(Aph, Bg, W2g, b2, partial);
    kRC<<<1, 256, 0, stream>>>(partial, W3, b3, W4, b4, out);
}

// Round 12
// 42.371 us; speedup vs baseline: 3.2973x; 1.2110x over previous
//
#include <hip/hip_runtime.h>
#include <hip/hip_fp16.h>

#define NN   512
#define D    128      // INPUT_DIM
#define HID  256      // HIDDEN_DIM
#define REL  128      // REL_DIM
#define ODIM 64

typedef __attribute__((ext_vector_type(4)))  float        f32x4;
typedef __attribute__((ext_vector_type(16))) float        f32x16;
typedef __attribute__((ext_vector_type(8)))  _Float16     f16x8;
typedef __attribute__((ext_vector_type(4)))  unsigned int u32x4;

union H8 { u32x4 u4; f16x8 h8; };

#define WAIT_VM(N) asm volatile("s_waitcnt vmcnt(" #N ")" ::: "memory")

__device__ __forceinline__ void cp16(void* l, const void* g) {
    __builtin_amdgcn_global_load_lds((const __attribute__((address_space(1))) unsigned int*)g,
                                     (__attribute__((address_space(3))) unsigned int*)l, 16, 0, 0);
}

// ---------------- kAW: blocks 0..127 compute A'(fp16, row-major) and B (fp16, frag-major Bg);
//                  blocks 128..143 pack W2 into 32x32x16 B-fragment order (W2g).
__global__ void kAW(const float* __restrict__ X, const float* __restrict__ W1,
                    const float* __restrict__ b1, _Float16* __restrict__ Aph,
                    _Float16* __restrict__ Bg,
                    const float* __restrict__ W2, _Float16* __restrict__ W2g) {
    int t = threadIdx.x;            // 0..255
    if (blockIdx.x >= 128) {        // ---- W2 pack
        int gid = (blockIdx.x - 128) * 256 + t;   // 0..4095
        int f = gid >> 6, l = gid & 63;
        int cg = f >> 4, ks = f & 15;
        H8 pkd;
#pragma unroll
        for (int e = 0; e < 8; ++e) {
            int k = ks * 16 + (l >> 5) * 8 + e;
            int c = cg * 32 + (l & 31);
            pkd.h8[e] = (_Float16)W2[k * REL + c];
        }
        *(u32x4*)&W2g[(size_t)gid * 8] = pkd.u4;
        return;
    }
    __shared__ float Xs[4][D];
    int r0 = blockIdx.x * 4;
#pragma unroll
    for (int q = 0; q < 2; ++q) {
        int idx = q * 256 + t;
        Xs[idx >> 7][idx & 127] = X[(r0 + (idx >> 7)) * D + (idx & 127)];
    }
    __syncthreads();
    float a[4], b[4];
    float b1c = b1[t];
#pragma unroll
    for (int r = 0; r < 4; ++r) { a[r] = b1c; b[r] = 0.f; }
#pragma unroll 4
    for (int k = 0; k < D; ++k) {
        float wt = W1[k * HID + t];
        float wb = W1[(D + k) * HID + t];
#pragma unroll
        for (int r = 0; r < 4; ++r) {
            a[r] += Xs[r][k] * wt;
            b[r] += Xs[r][k] * wb;
        }
    }
    int ks = t >> 4, hs = (t >> 3) & 1, e = t & 7;
#pragma unroll
    for (int r = 0; r < 4; ++r) {
        int row = r0 + r;
        Aph[row * HID + t] = (_Float16)a[r];
        Bg[(row >> 4) * 4096 + ks * 256 + hs * 128 + (row & 15) * 8 + e] = (_Float16)b[r];
    }
}

// ---------------- kB: 32x32x16 MFMA pair GEMM. Grid 512 (2/CU), 4 waves, R7 shape.
// blk: ch = blk&1 (64-col half), tg = blk>>1: jt = tg&31 (block-constant), itb = tg>>5.
// 8 units: i0 = itb*8 + u*64. Wave w owns rows {2w, 2w+1} (32 pairs = 2i x 16j).
// W2 (128 VGPR) + B (64 VGPR) register-resident — amdgpu_waves_per_eu(2,2) pins the
// allocator at 2 waves/EU so the ~230-VGPR live set fits WITHOUT AGPR-shuttle/remat.
// A staged per unit via cp16 into the wave's own 1KB slice, conflict-free layout:
// byte = ks*64 + row*32 + hs*16 (per-read addrs {0,16,32,48}+ks*64 -> 16-way broadcast).
__global__ __attribute__((amdgpu_flat_work_group_size(256, 256)))
           __attribute__((amdgpu_waves_per_eu(2, 2)))
void kB(const _Float16* __restrict__ Aph,
        const _Float16* __restrict__ Bg,
        const _Float16* __restrict__ W2g,
        const float* __restrict__ b2,
        float* __restrict__ partial) {
    __shared__ __align__(16) char smem[2][4096];   // A double-buffer: [buf][wave 1KB slices]
    __shared__ float redsh[4][2][32];

    int t = threadIdx.x, w = t >> 6, l = t & 63;
    int blk = blockIdx.x;
    int ch = blk & 1, tg = blk >> 1;
    int jt = tg & 31, itb = tg >> 5;   // j-tile (block-constant), i-tile base 0..7
    int l31 = l & 31, hs = l >> 5, j = l & 15;

    // W2 register fragments: 2 col-groups x 16 k-steps (128 VGPR), loaded once
    H8 w2r[2][16];
#pragma unroll
    for (int cgi = 0; cgi < 2; ++cgi)
#pragma unroll
        for (int ks = 0; ks < 16; ++ks)
            w2r[cgi][ks].u4 = *(const u32x4*)&W2g[(size_t)((((ch * 2 + cgi) * 16 + ks) * 64) + l) * 8];

    // B register fragments for this lane's (j, hs): 16 k-steps (64 VGPR), block-constant
    H8 brow[16];
#pragma unroll
    for (int ks = 0; ks < 16; ++ks)
        brow[ks].u4 = *(const u32x4*)&Bg[(size_t)jt * 4096 + ks * 256 + hs * 128 + j * 8];

    float b2c0 = b2[ch * 64 + l31];
    float b2c1 = b2[ch * 64 + 32 + l31];

    const f16x8 zero8 = (f16x8)(_Float16)0.f;
    float psum0 = 0.f, psum1 = 0.f;

    // staging source lane-map: LDS byte l*16 = ks*64 + row*32 + hs*16
    //   -> ks = l>>2, row = (l>>1)&1, hs = l&1
    int srow = (l >> 1) & 1, scol = ((l >> 2) << 4) + ((l & 1) << 3);

    // prologue: stage unit 0's A rows for this wave (1 KB)
    cp16(&smem[0][w * 1024 + l * 16], &Aph[(itb * 8 + 2 * w + srow) * HID + scol]);

#pragma unroll 1
    for (int u = 0; u < 8; ++u) {
        int cur = u & 1;
        if (u < 7) {
            int i0n = itb * 8 + (u + 1) * 64;
            cp16(&smem[cur ^ 1][w * 1024 + l * 16], &Aph[(i0n + 2 * w + srow) * HID + scol]);
            WAIT_VM(1);
        } else {
            WAIT_VM(0);
        }
        // no barrier: this wave reads only the slice it staged itself

        const char* abase = &smem[cur][w * 1024 + (l31 >> 4) * 32 + hs * 16];

        f32x16 acc0, acc1;
#pragma unroll
        for (int r = 0; r < 16; ++r) { acc0[r] = 0.f; acc1[r] = 0.f; }

#pragma unroll
        for (int ks = 0; ks < 16; ++ks) {
            H8 a = *(const H8*)(abase + ks * 64);
            f16x8 sum = a.h8 + brow[ks].h8;                       // v_pk_add_f16 x4
            H8 h; h.h8 = __builtin_elementwise_max(sum, zero8);   // v_pk_max_f16 x4
            acc0 = __builtin_amdgcn_mfma_f32_32x32x16_f16(h.h8, w2r[0][ks].h8, acc0, 0, 0, 0);
            acc1 = __builtin_amdgcn_mfma_f32_32x32x16_f16(h.h8, w2r[1][ks].h8, acc1, 0, 0, 0);
        }

        // per-unit epilogue: relu(acc + b2), sum over this lane's 16 pair-rows
        float s0 = 0.f, s1 = 0.f;
#pragma unroll
        for (int r = 0; r < 16; ++r) {
            s0 += fmaxf(acc0[r] + b2c0, 0.f);
            s1 += fmaxf(acc1[r] + b2c1, 0.f);
        }
        psum0 += s0; psum1 += s1;
    }

    // block reduction: combine row-halves, then the 4 waves
    psum0 += __shfl_xor(psum0, 32);
    psum1 += __shfl_xor(psum1, 32);
    if (l < 32) { redsh[w][0][l] = psum0; redsh[w][1][l] = psum1; }
    __syncthreads();
    if (w == 0 && l < 32) {
        float t0 = redsh[0][0][l] + redsh[1][0][l] + redsh[2][0][l] + redsh[3][0][l];
        float t1 = redsh[0][1][l] + redsh[1][1][l] + redsh[2][1][l] + redsh[3][1][l];
        partial[blk * 64 + l]      = t0;
        partial[blk * 64 + 32 + l] = t1;
    }
}

// ---------------- kRC: reduce 512 per-block partials -> R (mean), then final tiny MLP
__global__ void kRC(const float* __restrict__ partial,
                    const float* __restrict__ W3, const float* __restrict__ b3,
                    const float* __restrict__ W4, const float* __restrict__ b4,
                    float* __restrict__ out) {
    __shared__ float sh[256];
    __shared__ float Rsh[REL];
    __shared__ float t1[ODIM];
    int t = threadIdx.x;                 // 256
    int c = t & 127, g = t >> 7;
    int ch = c >> 6, cc = c & 63;
    float s = 0.f;
#pragma unroll 4
    for (int k = g * 128; k < g * 128 + 128; ++k)
        s += partial[(2 * k + ch) * 64 + cc];
    sh[t] = s;
    __syncthreads();
    if (t < 128) Rsh[t] = (sh[t] + sh[t + 128]) * (1.f / 262144.f);
    __syncthreads();
    if (t < ODIM) {
        float s3 = b3[t];
#pragma unroll 8
        for (int k = 0; k < REL; ++k) s3 += Rsh[k] * W3[k * ODIM + t];
        t1[t] = fmaxf(s3, 0.f);
    }
    __syncthreads();
    if (t < ODIM) {
        float s4 = b4[t];
#pragma unroll 8
        for (int k = 0; k < ODIM; ++k) s4 += t1[k] * W4[k * ODIM + t];
        out[t] = s4;
    }
}

extern "C" void kernel_launch(void* const* d_in, const int* in_sizes, int n_in,
                              void* d_out, int out_size, void* d_ws, size_t ws_size,
                              hipStream_t stream) {
    const float* X  = (const float*)d_in[0];
    const float* W1 = (const float*)d_in[1];
    const float* b1 = (const float*)d_in[2];
    const float* W2 = (const float*)d_in[3];
    const float* b2 = (const float*)d_in[4];
    const float* W3 = (const float*)d_in[5];
    const float* b3 = (const float*)d_in[6];
    const float* W4 = (const float*)d_in[7];
    const float* b4 = (const float*)d_in[8];
    float* out = (float*)d_out;

    char* ws = (char*)d_ws;
    _Float16* Aph     = (_Float16*)ws;                 // 512*256 fp16 = 256 KB
    _Float16* Bg      = (_Float16*)(ws + 262144);      // 32 jt * 8 KB = 256 KB
    _Float16* W2g     = (_Float16*)(ws + 524288);      // 64 frags * 1 KB = 64 KB
    float*    partial = (float*)(ws + 589824);         // 512*64 f32 = 128 KB

    kAW<<<144, 256, 0, stream>>>(X, W1, b1, Aph, Bg, W2, W2g);
    kB<<<512, 256, 0, stream>>>(Aph, Bg, W2g, b2, partial);
    kRC<<<1, 256, 0, stream>>>(partial, W3, b3, W4, b4, out);
}

// Round 13
// 41.015 us; speedup vs baseline: 3.4063x; 1.0331x over previous
//
#include <hip/hip_runtime.h>
#include <hip/hip_fp16.h>

#define NN   512
#define D    128      // INPUT_DIM
#define HID  256      // HIDDEN_DIM
#define REL  128      // REL_DIM
#define ODIM 64

typedef __attribute__((ext_vector_type(4)))  float        f32x4;
typedef __attribute__((ext_vector_type(16))) float        f32x16;
typedef __attribute__((ext_vector_type(8)))  _Float16     f16x8;
typedef __attribute__((ext_vector_type(4)))  unsigned int u32x4;

union H8 { u32x4 u4; f16x8 h8; };

#define WAIT_VM(N) asm volatile("s_waitcnt vmcnt(" #N ")" ::: "memory")

__device__ __forceinline__ void cp16(void* l, const void* g) {
    __builtin_amdgcn_global_load_lds((const __attribute__((address_space(1))) unsigned int*)g,
                                     (__attribute__((address_space(3))) unsigned int*)l, 16, 0, 0);
}

// ---------------- kAW: blocks 0..127 compute A'(fp16, row-major) and B (fp16, frag-major Bg);
//                  blocks 128..143 pack W2 into 32x32x16 B-fragment order (W2g).
__global__ void kAW(const float* __restrict__ X, const float* __restrict__ W1,
                    const float* __restrict__ b1, _Float16* __restrict__ Aph,
                    _Float16* __restrict__ Bg,
                    const float* __restrict__ W2, _Float16* __restrict__ W2g) {
    int t = threadIdx.x;            // 0..255
    if (blockIdx.x >= 128) {        // ---- W2 pack
        int gid = (blockIdx.x - 128) * 256 + t;   // 0..4095
        int f = gid >> 6, l = gid & 63;
        int cg = f >> 4, ks = f & 15;
        H8 pkd;
#pragma unroll
        for (int e = 0; e < 8; ++e) {
            int k = ks * 16 + (l >> 5) * 8 + e;
            int c = cg * 32 + (l & 31);
            pkd.h8[e] = (_Float16)W2[k * REL + c];
        }
        *(u32x4*)&W2g[(size_t)gid * 8] = pkd.u4;
        return;
    }
    __shared__ float Xs[4][D];
    int r0 = blockIdx.x * 4;
#pragma unroll
    for (int q = 0; q < 2; ++q) {
        int idx = q * 256 + t;
        Xs[idx >> 7][idx & 127] = X[(r0 + (idx >> 7)) * D + (idx & 127)];
    }
    __syncthreads();
    float a[4], b[4];
    float b1c = b1[t];
#pragma unroll
    for (int r = 0; r < 4; ++r) { a[r] = b1c; b[r] = 0.f; }
#pragma unroll 4
    for (int k = 0; k < D; ++k) {
        float wt = W1[k * HID + t];
        float wb = W1[(D + k) * HID + t];
#pragma unroll
        for (int r = 0; r < 4; ++r) {
            a[r] += Xs[r][k] * wt;
            b[r] += Xs[r][k] * wb;
        }
    }
    int ks = t >> 4, hs = (t >> 3) & 1, e = t & 7;
#pragma unroll
    for (int r = 0; r < 4; ++r) {
        int row = r0 + r;
        Aph[row * HID + t] = (_Float16)a[r];
        Bg[(row >> 4) * 4096 + ks * 256 + hs * 128 + (row & 15) * 8 + e] = (_Float16)b[r];
    }
}

// ---------------- kB: 32x32x16 MFMA pair GEMM. Grid 512 (2/CU), 4 waves, R7/R12 shape.
// blk: ch = blk&1 (64-col half), tg = blk>>1: jt = tg&31 (block-constant), itb = tg>>5.
// 8 units: i0 = itb*8 + u*64. Wave w owns rows {2w, 2w+1} (32 pairs = 2i x 16j).
// PROLOGUE FIX (R13): W2g ch-slice (32 KB, contiguous) + Bg jt-slice (8 KB) staged
// cooperatively via global_load_lds (10 coalesced cp16/thread instead of 48 scattered
// dwordx4/lane -> 4.8x less global broadcast traffic), then per-lane ds_read to regs.
__global__ __attribute__((amdgpu_flat_work_group_size(256, 256)))
           __attribute__((amdgpu_waves_per_eu(2, 2)))
void kB(const _Float16* __restrict__ Aph,
        const _Float16* __restrict__ Bg,
        const _Float16* __restrict__ W2g,
        const float* __restrict__ b2,
        float* __restrict__ partial) {
    __shared__ __align__(16) char w2b[40960];      // [0,32KB): W2 frags; [32KB,40KB): B slice
    __shared__ __align__(16) char smem[2][4096];   // A double-buffer: [buf][wave 1KB slices]
    __shared__ float redsh[4][2][32];

    int t = threadIdx.x, w = t >> 6, l = t & 63;
    int blk = blockIdx.x;
    int ch = blk & 1, tg = blk >> 1;
    int jt = tg & 31, itb = tg >> 5;   // j-tile (block-constant), i-tile base 0..7
    int l31 = l & 31, hs = l >> 5, j = l & 15;

    // ---- cooperative stage: W2g[ch*32768 .. +32768) and Bg[jt*8192 .. +8192) (bytes)
    {
        const char* w2src = (const char*)W2g + (size_t)ch * 32768;
        const char* bsrc  = (const char*)Bg  + (size_t)jt * 8192;
#pragma unroll
        for (int q = 0; q < 8; ++q) {
            int c16 = q * 256 + t;
            cp16(&w2b[c16 * 16], w2src + c16 * 16);
        }
#pragma unroll
        for (int q = 0; q < 2; ++q) {
            int c16 = q * 256 + t;
            cp16(&w2b[32768 + c16 * 16], bsrc + c16 * 16);
        }
        WAIT_VM(0);
        __syncthreads();
    }

    // W2 register fragments: 2 col-groups x 16 k-steps (128 regs), from LDS
    H8 w2r[2][16];
#pragma unroll
    for (int cgi = 0; cgi < 2; ++cgi)
#pragma unroll
        for (int ks = 0; ks < 16; ++ks)
            w2r[cgi][ks].u4 = *(const u32x4*)&w2b[(cgi * 16 + ks) * 1024 + l * 16];

    // B register fragments for this lane's (j, hs): 16 k-steps (64 regs), from LDS
    H8 brow[16];
#pragma unroll
    for (int ks = 0; ks < 16; ++ks)
        brow[ks].u4 = *(const u32x4*)&w2b[32768 + ks * 512 + hs * 256 + j * 16];

    float b2c0 = b2[ch * 64 + l31];
    float b2c1 = b2[ch * 64 + 32 + l31];

    const f16x8 zero8 = (f16x8)(_Float16)0.f;
    float psum0 = 0.f, psum1 = 0.f;

    // A staging lane-map: LDS byte l*16 = ks*64 + row*32 + hs*16
    int srow = (l >> 1) & 1, scol = ((l >> 2) << 4) + ((l & 1) << 3);

    // prologue: stage unit 0's A rows for this wave (1 KB)
    cp16(&smem[0][w * 1024 + l * 16], &Aph[(itb * 8 + 2 * w + srow) * HID + scol]);

#pragma unroll 1
    for (int u = 0; u < 8; ++u) {
        int cur = u & 1;
        if (u < 7) {
            int i0n = itb * 8 + (u + 1) * 64;
            cp16(&smem[cur ^ 1][w * 1024 + l * 16], &Aph[(i0n + 2 * w + srow) * HID + scol]);
            WAIT_VM(1);
        } else {
            WAIT_VM(0);
        }
        // no barrier: this wave reads only the slice it staged itself

        const char* abase = &smem[cur][w * 1024 + (l31 >> 4) * 32 + hs * 16];

        f32x16 acc0, acc1;
#pragma unroll
        for (int r = 0; r < 16; ++r) { acc0[r] = 0.f; acc1[r] = 0.f; }

#pragma unroll
        for (int ks = 0; ks < 16; ++ks) {
            H8 a = *(const H8*)(abase + ks * 64);
            f16x8 sum = a.h8 + brow[ks].h8;                       // v_pk_add_f16 x4
            H8 h; h.h8 = __builtin_elementwise_max(sum, zero8);   // v_pk_max_f16 x4
            acc0 = __builtin_amdgcn_mfma_f32_32x32x16_f16(h.h8, w2r[0][ks].h8, acc0, 0, 0, 0);
            acc1 = __builtin_amdgcn_mfma_f32_32x32x16_f16(h.h8, w2r[1][ks].h8, acc1, 0, 0, 0);
        }

        // per-unit epilogue: relu(acc + b2), sum over this lane's 16 pair-rows
        float s0 = 0.f, s1 = 0.f;
#pragma unroll
        for (int r = 0; r < 16; ++r) {
            s0 += fmaxf(acc0[r] + b2c0, 0.f);
            s1 += fmaxf(acc1[r] + b2c1, 0.f);
        }
        psum0 += s0; psum1 += s1;
    }

    // block reduction: combine row-halves, then the 4 waves
    psum0 += __shfl_xor(psum0, 32);
    psum1 += __shfl_xor(psum1, 32);
    if (l < 32) { redsh[w][0][l] = psum0; redsh[w][1][l] = psum1; }
    __syncthreads();
    if (w == 0 && l < 32) {
        float t0 = redsh[0][0][l] + redsh[1][0][l] + redsh[2][0][l] + redsh[3][0][l];
        float t1 = redsh[0][1][l] + redsh[1][1][l] + redsh[2][1][l] + redsh[3][1][l];
        partial[blk * 64 + l]      = t0;
        partial[blk * 64 + 32 + l] = t1;
    }
}

// ---------------- kRC: reduce 512 per-block partials -> R (mean), then final tiny MLP
__global__ void kRC(const float* __restrict__ partial,
                    const float* __restrict__ W3, const float* __restrict__ b3,
                    const float* __restrict__ W4, const float* __restrict__ b4,
                    float* __restrict__ out) {
    __shared__ float sh[256];
    __shared__ float Rsh[REL];
    __shared__ float t1[ODIM];
    int t = threadIdx.x;                 // 256
    int c = t & 127, g = t >> 7;
    int ch = c >> 6, cc = c & 63;
    float s = 0.f;
#pragma unroll 4
    for (int k = g * 128; k < g * 128 + 128; ++k)
        s += partial[(2 * k + ch) * 64 + cc];
    sh[t] = s;
    __syncthreads();
    if (t < 128) Rsh[t] = (sh[t] + sh[t + 128]) * (1.f / 262144.f);
    __syncthreads();
    if (t < ODIM) {
        float s3 = b3[t];
#pragma unroll 8
        for (int k = 0; k < REL; ++k) s3 += Rsh[k] * W3[k * ODIM + t];
        t1[t] = fmaxf(s3, 0.f);
    }
    __syncthreads();
    if (t < ODIM) {
        float s4 = b4[t];
#pragma unroll 8
        for (int k = 0; k < ODIM; ++k) s4 += t1[k] * W4[k * ODIM + t];
        out[t] = s4;
    }
}

extern "C" void kernel_launch(void* const* d_in, const int* in_sizes, int n_in,
                              void* d_out, int out_size, void* d_ws, size_t ws_size,
                              hipStream_t stream) {
    const float* X  = (const float*)d_in[0];
    const float* W1 = (const float*)d_in[1];
    const float* b1 = (const float*)d_in[2];
    const float* W2 = (const float*)d_in[3];
    const float* b2 = (const float*)d_in[4];
    const float* W3 = (const float*)d_in[5];
    const float* b3 = (const float*)d_in[6];
    const float* W4 = (const float*)d_in[7];
    const float* b4 = (const float*)d_in[8];
    float* out = (float*)d_out;

    char* ws = (char*)d_ws;
    _Float16* Aph     = (_Float16*)ws;                 // 512*256 fp16 = 256 KB
    _Float16* Bg      = (_Float16*)(ws + 262144);      // 32 jt * 8 KB = 256 KB
    _Float16* W2g     = (_Float16*)(ws + 524288);      // 64 frags * 1 KB = 64 KB
    float*    partial = (float*)(ws + 589824);         // 512*64 f32 = 128 KB

    kAW<<<144, 256, 0, stream>>>(X, W1, b1, Aph, Bg, W2, W2g);
    kB<<<512, 256, 0, stream>>>(Aph, Bg, W2g, b2, partial);
    kRC<<<1, 256, 0, stream>>>(partial, W3, b3, W4, b4, out);
}